// Round 1
// baseline (786.332 us; speedup 1.0000x reference)
//
#include <hip/hip_runtime.h>
#include <stdint.h>

// Problem constants
#define L_Q 128
#define N_B 8
#define S_P 16384
#define C_D 256   // C = B = V = 256

// Workspace layout (float offsets):
//   qT    [N][B][L]   262144 @ 0        (q_proj transposed per-n: qT[n][b][l])
//   WqT   [C][B]      65536  @ 262144
//   WpT   [C][B]      65536  @ 327680
//   WvT   [B][V]      65536  @ 393216
//   WoT   [V][C]      65536  @ 458752
//   packed u64[N*L]          @ float-off 524288 (byte 2097152)

// ---------------------------------------------------------------------------
// Kernel 0: transpose the four weight matrices (for coalesced streaming) and
// zero the packed-argmax buffer (ws is re-poisoned to 0xAA before every call).
__global__ __launch_bounds__(256) void k_prep(
    const float* __restrict__ Wq, const float* __restrict__ Wp,
    const float* __restrict__ Wv, const float* __restrict__ Wo,
    float* __restrict__ WqT, float* __restrict__ WpT,
    float* __restrict__ WvT, float* __restrict__ WoT,
    unsigned long long* __restrict__ packed) {
  int idx = (blockIdx.x << 8) + threadIdx.x;   // 0..65535
  int r = idx >> 8, c = idx & 255;
  int t = (c << 8) + r;
  WqT[t] = Wq[idx];
  WpT[t] = Wp[idx];
  WvT[t] = Wv[idx];
  WoT[t] = Wo[idx];
  if (idx < N_B * L_Q) packed[idx] = 0ull;  // any real logit packs to > 0
}

// ---------------------------------------------------------------------------
// Kernel A: q_proj. 4 rows (l*8+n flat) per block, 256 blocks.
// qT[n][b][l] = bq[b] + sum_c (tgt+qpos)[l,n,c] * Wq[b,c]
__global__ __launch_bounds__(256) void k_qproj(
    const float* __restrict__ tgt, const float* __restrict__ qpos,
    const float* __restrict__ WqT, const float* __restrict__ bq,
    float* __restrict__ qT) {
  __shared__ __align__(16) float q_lds[4][256];
  int tid = threadIdx.x;
  int r0 = blockIdx.x << 2;
  #pragma unroll
  for (int j = 0; j < 4; ++j) {
    int p = (j << 8) + tid;
    int rl = p >> 8, c = p & 255;
    int g = ((r0 + rl) << 8) + c;      // (l*8+n)*256+c is flat row-major
    q_lds[rl][c] = tgt[g] + qpos[g];
  }
  __syncthreads();
  float bqv = bq[tid];
  float a0 = bqv, a1 = bqv, a2 = bqv, a3 = bqv;
  #pragma unroll 4
  for (int c = 0; c < 256; ++c) {
    float w = WqT[(c << 8) + tid];     // coalesced, L2-resident
    a0 = fmaf(w, q_lds[0][c], a0);
    a1 = fmaf(w, q_lds[1][c], a1);
    a2 = fmaf(w, q_lds[2][c], a2);
    a3 = fmaf(w, q_lds[3][c], a3);
  }
  float av[4] = {a0, a1, a2, a3};
  #pragma unroll
  for (int rl = 0; rl < 4; ++rl) {
    int r = r0 + rl;
    int l = r >> 3, nn = r & 7;
    qT[(nn << 15) + (tid << 7) + l] = av[rl];
  }
}

// ---------------------------------------------------------------------------
// Kernel B (main): per block: one n, 64 s-rows.
//   stage k tile transposed into LDS kT[c][s]  (64 KB, stride 64 -> reads are
//   broadcasts / 2-way, free)
//   GEMM1: k_proj tile in registers (8s x 8b per thread), + bias, L2 norms via
//   shfl over the 32 b-group lanes, normalized tile written back as kT[b][s]
//   GEMM2: logits (128 l x 64 s) vs qT[n][b][l], 8l x 4s per thread
//   argmax over s fused: shfl-reduce + packed u64 atomicMax (ties -> min s)
__global__ __launch_bounds__(256, 2) void k_main(
    const float* __restrict__ memory, const float* __restrict__ pos,
    const float* __restrict__ WpT, const float* __restrict__ bp,
    const float* __restrict__ qT, unsigned long long* __restrict__ packed) {
  __shared__ __align__(16) float kT[256][64];   // exactly 64 KB
  int tid = threadIdx.x;
  int n = blockIdx.y;
  int s_base = blockIdx.x << 6;   // 64 s-rows per block

  // ---- stage: load (memory+pos) rows, store transposed ----
  #pragma unroll
  for (int j = 0; j < 16; ++j) {
    int f = (j << 8) + tid;           // float4 index in tile
    int sl = f >> 6, c4 = f & 63;
    int g = (((s_base + sl) << 3) + n) << 8 | (c4 << 2);
    const float4 m4 = *(const float4*)(memory + g);
    const float4 p4 = *(const float4*)(pos + g);
    kT[(c4 << 2) + 0][sl] = m4.x + p4.x;
    kT[(c4 << 2) + 1][sl] = m4.y + p4.y;
    kT[(c4 << 2) + 2][sl] = m4.z + p4.z;
    kT[(c4 << 2) + 3][sl] = m4.w + p4.w;
  }
  __syncthreads();

  // ---- GEMM1: k_proj = kT^T * WpT   (acc[i=s][j=b]) ----
  int bg = tid & 31, sg = tid >> 5;
  int b0 = bg << 3, s0 = sg << 3;
  float acc[8][8];
  #pragma unroll
  for (int i = 0; i < 8; ++i)
    #pragma unroll
    for (int j = 0; j < 8; ++j) acc[i][j] = 0.f;

  for (int c = 0; c < 256; ++c) {
    const float4 w0 = *(const float4*)(WpT + (c << 8) + b0);
    const float4 w1 = *(const float4*)(WpT + (c << 8) + b0 + 4);
    const float4 k0 = *(const float4*)(&kT[c][s0]);
    const float4 k1 = *(const float4*)(&kT[c][s0 + 4]);
    float wv[8] = {w0.x, w0.y, w0.z, w0.w, w1.x, w1.y, w1.z, w1.w};
    float kv[8] = {k0.x, k0.y, k0.z, k0.w, k1.x, k1.y, k1.z, k1.w};
    #pragma unroll
    for (int i = 0; i < 8; ++i)
      #pragma unroll
      for (int j = 0; j < 8; ++j)
        acc[i][j] = fmaf(kv[i], wv[j], acc[i][j]);
  }

  // bias + row norms
  const float4 bpa = *(const float4*)(bp + b0);
  const float4 bpb = *(const float4*)(bp + b0 + 4);
  float bpv[8] = {bpa.x, bpa.y, bpa.z, bpa.w, bpb.x, bpb.y, bpb.z, bpb.w};
  float n2[8];
  #pragma unroll
  for (int i = 0; i < 8; ++i) {
    float s = 0.f;
    #pragma unroll
    for (int j = 0; j < 8; ++j) {
      acc[i][j] += bpv[j];
      s = fmaf(acc[i][j], acc[i][j], s);
    }
    n2[i] = s;
  }
  #pragma unroll
  for (int off = 1; off < 32; off <<= 1)
    #pragma unroll
    for (int i = 0; i < 8; ++i) n2[i] += __shfl_xor(n2[i], off, 64);
  float rn[8];
  #pragma unroll
  for (int i = 0; i < 8; ++i) rn[i] = 1.f / fmaxf(sqrtf(n2[i]), 1e-12f);

  __syncthreads();   // everyone done reading kT as k
  // write normalized k_proj transposed: kT[b][s]
  #pragma unroll
  for (int j = 0; j < 8; ++j)
    #pragma unroll
    for (int i = 0; i < 8; ++i)
      kT[b0 + j][s0 + i] = acc[i][j] * rn[i];
  __syncthreads();

  // ---- GEMM2: logits[l][s] = sum_b qT[n][b][l] * kT[b][s] ----
  int sg2 = tid & 15, lg2 = tid >> 4;
  int s20 = sg2 << 2, l0 = lg2 << 3;
  const float* qTn = qT + (n << 15);
  float acc2[8][4];
  #pragma unroll
  for (int l = 0; l < 8; ++l)
    #pragma unroll
    for (int s = 0; s < 4; ++s) acc2[l][s] = 0.f;

  for (int b = 0; b < 256; ++b) {
    const float4 q0 = *(const float4*)(qTn + (b << 7) + l0);
    const float4 q1 = *(const float4*)(qTn + (b << 7) + l0 + 4);
    const float4 k4 = *(const float4*)(&kT[b][s20]);
    float qv[8] = {q0.x, q0.y, q0.z, q0.w, q1.x, q1.y, q1.z, q1.w};
    float kv[4] = {k4.x, k4.y, k4.z, k4.w};
    #pragma unroll
    for (int l = 0; l < 8; ++l)
      #pragma unroll
      for (int s = 0; s < 4; ++s)
        acc2[l][s] = fmaf(qv[l], kv[s], acc2[l][s]);
  }

  // ---- fused argmax over the 64 s in this tile ----
  float mv[8];
  int mi[8];
  #pragma unroll
  for (int l = 0; l < 8; ++l) {
    mv[l] = acc2[l][0];
    mi[l] = s_base + s20;
    #pragma unroll
    for (int s = 1; s < 4; ++s)
      if (acc2[l][s] > mv[l]) { mv[l] = acc2[l][s]; mi[l] = s_base + s20 + s; }
  }
  #pragma unroll
  for (int off = 1; off < 16; off <<= 1) {
    #pragma unroll
    for (int l = 0; l < 8; ++l) {
      float ov = __shfl_xor(mv[l], off, 64);
      int oi = __shfl_xor(mi[l], off, 64);
      if (ov > mv[l] || (ov == mv[l] && oi < mi[l])) { mv[l] = ov; mi[l] = oi; }
    }
  }
  #pragma unroll
  for (int l = 0; l < 8; ++l) {
    if ((tid & 15) == l) {
      unsigned int ub = __float_as_uint(mv[l]);
      ub = (ub & 0x80000000u) ? ~ub : (ub | 0x80000000u);
      unsigned long long pk =
          ((unsigned long long)ub << 32) |
          (unsigned long long)(16383u - (unsigned int)mi[l]);
      atomicMax(packed + (n << 7) + l0 + l, pk);
    }
  }
}

// ---------------------------------------------------------------------------
// Kernel D: gather winners, recompute k_proj/v_proj for the 1024 selected
// rows, output projection, residual, LayerNorm. 4 rows per block, 256 blocks.
__global__ __launch_bounds__(256) void k_final(
    const float* __restrict__ tgt,
    const float* __restrict__ memory, const float* __restrict__ pos,
    const float* __restrict__ WpT, const float* __restrict__ bp,
    const float* __restrict__ WvT, const float* __restrict__ bv,
    const float* __restrict__ WoT, const float* __restrict__ bo,
    const float* __restrict__ gamma, const float* __restrict__ beta,
    const unsigned long long* __restrict__ packed, float* __restrict__ out) {
  __shared__ __align__(16) float buf0[4][256];  // k rows
  __shared__ __align__(16) float buf1[4][256];  // k_proj rows
  __shared__ __align__(16) float buf2[4][256];  // v rows
  __shared__ float red[4][4][2];
  int tid = threadIdx.x;
  int r0 = blockIdx.x << 2;

  #pragma unroll
  for (int j = 0; j < 4; ++j) {
    int p = (j << 8) + tid;
    int rl = p >> 8, c = p & 255;
    int r = r0 + rl;
    int l = r >> 3, nn = r & 7;
    unsigned long long pk = packed[(nn << 7) + l];
    int sstar = 16383 - (int)(unsigned int)(pk & 0xffffffffu);
    int g = ((sstar << 3) + nn) << 8 | c;
    buf0[rl][c] = memory[g] + pos[g];
  }
  __syncthreads();

  float a[4];
  // stage 1: k_proj
  { float b0v = bp[tid];
    #pragma unroll
    for (int rl = 0; rl < 4; ++rl) a[rl] = b0v; }
  #pragma unroll 4
  for (int c = 0; c < 256; ++c) {
    float w = WpT[(c << 8) + tid];
    #pragma unroll
    for (int rl = 0; rl < 4; ++rl) a[rl] = fmaf(w, buf0[rl][c], a[rl]);
  }
  #pragma unroll
  for (int rl = 0; rl < 4; ++rl) buf1[rl][tid] = a[rl];
  __syncthreads();

  // stage 2: v_proj
  { float b0v = bv[tid];
    #pragma unroll
    for (int rl = 0; rl < 4; ++rl) a[rl] = b0v; }
  #pragma unroll 4
  for (int c = 0; c < 256; ++c) {
    float w = WvT[(c << 8) + tid];
    #pragma unroll
    for (int rl = 0; rl < 4; ++rl) a[rl] = fmaf(w, buf1[rl][c], a[rl]);
  }
  #pragma unroll
  for (int rl = 0; rl < 4; ++rl) buf2[rl][tid] = a[rl];
  __syncthreads();

  // stage 3: output projection + residual
  { float b0v = bo[tid];
    #pragma unroll
    for (int rl = 0; rl < 4; ++rl) a[rl] = b0v; }
  #pragma unroll 4
  for (int c = 0; c < 256; ++c) {
    float w = WoT[(c << 8) + tid];
    #pragma unroll
    for (int rl = 0; rl < 4; ++rl) a[rl] = fmaf(w, buf2[rl][c], a[rl]);
  }
  float x[4];
  #pragma unroll
  for (int rl = 0; rl < 4; ++rl)
    x[rl] = tgt[((r0 + rl) << 8) + tid] + a[rl];

  // LayerNorm over the 256 threads, per row
  float s1[4], s2[4];
  #pragma unroll
  for (int rl = 0; rl < 4; ++rl) { s1[rl] = x[rl]; s2[rl] = x[rl] * x[rl]; }
  #pragma unroll
  for (int off = 1; off < 64; off <<= 1)
    #pragma unroll
    for (int rl = 0; rl < 4; ++rl) {
      s1[rl] += __shfl_xor(s1[rl], off, 64);
      s2[rl] += __shfl_xor(s2[rl], off, 64);
    }
  int wv = tid >> 6, ln = tid & 63;
  if (ln == 0) {
    #pragma unroll
    for (int rl = 0; rl < 4; ++rl) { red[wv][rl][0] = s1[rl]; red[wv][rl][1] = s2[rl]; }
  }
  __syncthreads();
  float g = gamma[tid], be = beta[tid];
  #pragma unroll
  for (int rl = 0; rl < 4; ++rl) {
    float S1 = red[0][rl][0] + red[1][rl][0] + red[2][rl][0] + red[3][rl][0];
    float S2 = red[0][rl][1] + red[1][rl][1] + red[2][rl][1] + red[3][rl][1];
    float mu = S1 * (1.f / 256.f);
    float var = S2 * (1.f / 256.f) - mu * mu;
    float rs = rsqrtf(var + 1e-5f);
    out[((r0 + rl) << 8) + tid] = (x[rl] - mu) * rs * g + be;
  }
}

// ---------------------------------------------------------------------------
extern "C" void kernel_launch(void* const* d_in, const int* in_sizes, int n_in,
                              void* d_out, int out_size, void* d_ws, size_t ws_size,
                              hipStream_t stream) {
  const float* tgt    = (const float*)d_in[0];
  const float* memory = (const float*)d_in[1];
  const float* pos    = (const float*)d_in[2];
  const float* qpos   = (const float*)d_in[3];
  const float* Wq     = (const float*)d_in[4];
  const float* bq     = (const float*)d_in[5];
  const float* Wp     = (const float*)d_in[6];
  const float* bp     = (const float*)d_in[7];
  const float* Wv     = (const float*)d_in[8];
  const float* bv     = (const float*)d_in[9];
  const float* Wo     = (const float*)d_in[10];
  const float* bo     = (const float*)d_in[11];
  const float* gamma  = (const float*)d_in[12];
  const float* beta   = (const float*)d_in[13];

  float* ws = (float*)d_ws;
  float* qT  = ws;
  float* WqT = ws + 262144;
  float* WpT = ws + 327680;
  float* WvT = ws + 393216;
  float* WoT = ws + 458752;
  unsigned long long* packed = (unsigned long long*)(ws + 524288);
  float* out = (float*)d_out;

  k_prep<<<256, 256, 0, stream>>>(Wq, Wp, Wv, Wo, WqT, WpT, WvT, WoT, packed);
  k_qproj<<<256, 256, 0, stream>>>(tgt, qpos, WqT, bq, qT);
  dim3 gb(S_P / 64, N_B);
  k_main<<<gb, 256, 0, stream>>>(memory, pos, WpT, bp, qT, packed);
  k_final<<<256, 256, 0, stream>>>(tgt, memory, pos, WpT, bp, WvT, bv,
                                   WoT, bo, gamma, beta, packed, out);
}

// Round 3
// 503.188 us; speedup vs baseline: 1.5627x; 1.5627x over previous
//
#include <hip/hip_runtime.h>
#include <stdint.h>

// Problem constants: L=128, N=8, S=16384, C=B=V=256
#define L_Q 128
#define N_B 8
#define S_P 16384

typedef _Float16 half8 __attribute__((ext_vector_type(8)));
typedef float f32x4 __attribute__((ext_vector_type(4)));

// Workspace layout (float offsets) — total 526336 floats = 2,105,344 bytes
// (exactly the round-0-proven footprint):
//   WpT   fp32 [C][B]      65536 @ 0        (k_final, coalesced [c][b])
//   WvT   fp32 [B][V]      65536 @ 65536
//   WoT   fp32 [V][C]      65536 @ 131072
//   Wp_hi f16  [B][C]      32768 @ 196608   (k_main GEMM1 B-operand)
//   Wp_lo f16  [B][C]      32768 @ 229376
//   q_hi  f16  [N][L][B]  131072 @ 262144   (k_main GEMM2 A-operand)
//   q_lo  f16  [N][L][B]  131072 @ 393216
//   packed u64 [N*L]        2048 @ 524288

// ---------------------------------------------------------------------------
__global__ __launch_bounds__(256) void k_prep(
    const float* __restrict__ Wp, const float* __restrict__ Wv,
    const float* __restrict__ Wo,
    float* __restrict__ WpT, float* __restrict__ WvT, float* __restrict__ WoT,
    _Float16* __restrict__ Wp_hi, _Float16* __restrict__ Wp_lo,
    unsigned long long* __restrict__ packed) {
  int idx = (blockIdx.x << 8) + threadIdx.x;   // 0..65535
  int r = idx >> 8, c = idx & 255;
  int t = (c << 8) + r;
  float wp = Wp[idx];
  WpT[t] = wp;
  WvT[t] = Wv[idx];
  WoT[t] = Wo[idx];
  _Float16 h = (_Float16)wp;
  Wp_hi[idx] = h;                        // [b][c], no transpose
  Wp_lo[idx] = (_Float16)(wp - (float)h);
  if (idx < N_B * L_Q) packed[idx] = 0ull;  // any real logit packs to > 0
}

// ---------------------------------------------------------------------------
// q_proj fp32 on VALU; Wq read directly (row per thread, per-thread contiguous
// float4 — L1/L2 resident). Emits split-f16 q_hi/q_lo in [n][l][b] layout.
__global__ __launch_bounds__(256) void k_qproj(
    const float* __restrict__ tgt, const float* __restrict__ qpos,
    const float* __restrict__ Wq, const float* __restrict__ bq,
    _Float16* __restrict__ q_hi, _Float16* __restrict__ q_lo) {
  __shared__ __align__(16) float q_lds[4][256];
  int tid = threadIdx.x;
  int r0 = blockIdx.x << 2;
  #pragma unroll
  for (int j = 0; j < 4; ++j) {
    int p = (j << 8) + tid;
    int rl = p >> 8, c = p & 255;
    int g = ((r0 + rl) << 8) + c;        // (l*8+n) row-major
    q_lds[rl][c] = tgt[g] + qpos[g];
  }
  __syncthreads();
  float bqv = bq[tid];
  float a0 = bqv, a1 = bqv, a2 = bqv, a3 = bqv;
  #pragma unroll 4
  for (int c = 0; c < 256; c += 4) {
    float4 w = *(const float4*)(Wq + (tid << 8) + c);
    a0 = fmaf(w.x, q_lds[0][c], fmaf(w.y, q_lds[0][c+1],
         fmaf(w.z, q_lds[0][c+2], fmaf(w.w, q_lds[0][c+3], a0))));
    a1 = fmaf(w.x, q_lds[1][c], fmaf(w.y, q_lds[1][c+1],
         fmaf(w.z, q_lds[1][c+2], fmaf(w.w, q_lds[1][c+3], a1))));
    a2 = fmaf(w.x, q_lds[2][c], fmaf(w.y, q_lds[2][c+1],
         fmaf(w.z, q_lds[2][c+2], fmaf(w.w, q_lds[2][c+3], a2))));
    a3 = fmaf(w.x, q_lds[3][c], fmaf(w.y, q_lds[3][c+1],
         fmaf(w.z, q_lds[3][c+2], fmaf(w.w, q_lds[3][c+3], a3))));
  }
  float av[4] = {a0, a1, a2, a3};
  #pragma unroll
  for (int rl = 0; rl < 4; ++rl) {
    int r = r0 + rl;
    int l = r >> 3, nn = r & 7;
    int o = (((nn << 7) + l) << 8) + tid;
    _Float16 h = (_Float16)av[rl];
    q_hi[o] = h;
    q_lo[o] = (_Float16)(av[rl] - (float)h);
  }
}

// ---------------------------------------------------------------------------
// Main fused kernel: per block one n, 64 s-rows.
//   stage (memory+pos) -> split-f16 in LDS (xor-swizzled 16B chunks)
//   GEMM1 (MFMA, 3-term split): k_proj 64x256, + bias, fp32 row norms
//   writeback normalized k into same LDS ([s][b], GEMM2 B-operand layout)
//   GEMM2 (MFMA, 3-term split): logits 128x64, fused argmax + u64 atomicMax
__global__ __launch_bounds__(256, 2) void k_main(
    const float* __restrict__ memory, const float* __restrict__ pos,
    const _Float16* __restrict__ Wp_hi, const _Float16* __restrict__ Wp_lo,
    const float* __restrict__ bp,
    const _Float16* __restrict__ q_hi, const _Float16* __restrict__ q_lo,
    unsigned long long* __restrict__ packed) {
  __shared__ __align__(16) unsigned short smu[2 * 64 * 256];  // 64 KB
  unsigned short* a_hi = smu;            // [64][256] f16 bits (swizzled)
  unsigned short* a_lo = smu + 16384;

  int tid = threadIdx.x;
  int w = tid >> 6;                      // wave 0..3
  int lane = tid & 63;
  int l15 = lane & 15, quad = lane >> 4;
  int n = blockIdx.y;
  int s_base = blockIdx.x << 6;          // 64 s-rows per block

  // ---- stage A-tile: (memory+pos) -> f16 hi/lo, chunk-swizzled ----
  {
    int half = tid >> 5;                 // 0..7
    int chunk = tid & 31;                // 8-element chunk id
    int c0 = chunk << 3;
    #pragma unroll
    for (int it = 0; it < 8; ++it) {
      int srow = (it << 3) + half;
      int g = (((s_base + srow) << 3) + n) * 256 + c0;
      float4 m0 = *(const float4*)(memory + g);
      float4 m1 = *(const float4*)(memory + g + 4);
      float4 p0 = *(const float4*)(pos + g);
      float4 p1 = *(const float4*)(pos + g + 4);
      float f[8] = {m0.x + p0.x, m0.y + p0.y, m0.z + p0.z, m0.w + p0.w,
                    m1.x + p1.x, m1.y + p1.y, m1.z + p1.z, m1.w + p1.w};
      half8 hv, lv;
      #pragma unroll
      for (int j = 0; j < 8; ++j) {
        _Float16 h = (_Float16)f[j];
        hv[j] = h;
        lv[j] = (_Float16)(f[j] - (float)h);
      }
      int p = chunk ^ (srow & 15);
      *(half8*)(a_hi + (srow << 8) + (p << 3)) = hv;
      *(half8*)(a_lo + (srow << 8) + (p << 3)) = lv;
    }
  }
  __syncthreads();

  // ---- GEMM1: D[s][b] = sum_c k[s][c] * Wp[b][c]  (3-term split f16) ----
  f32x4 acc1[4][4];   // [m: s-tile][bn: b-tile]; wave w owns b in [w*64,w*64+64)
  #pragma unroll
  for (int m = 0; m < 4; ++m)
    #pragma unroll
    for (int bn = 0; bn < 4; ++bn) acc1[m][bn] = (f32x4)(0.0f);

  for (int kk = 0; kk < 8; ++kk) {
    int cofs = (kk << 5) + (quad << 3);           // c base for this lane
    half8 ah[4], al[4];
    #pragma unroll
    for (int m = 0; m < 4; ++m) {
      int s = (m << 4) + l15;
      int p = (cofs >> 3) ^ l15;                  // chunk swizzle
      ah[m] = *(const half8*)(a_hi + (s << 8) + (p << 3));
      al[m] = *(const half8*)(a_lo + (s << 8) + (p << 3));
    }
    #pragma unroll
    for (int bn = 0; bn < 4; ++bn) {
      int b = (w << 6) + (bn << 4) + l15;
      half8 wh = *(const half8*)(Wp_hi + (b << 8) + cofs);
      half8 wl = *(const half8*)(Wp_lo + (b << 8) + cofs);
      #pragma unroll
      for (int m = 0; m < 4; ++m) {
        acc1[m][bn] = __builtin_amdgcn_mfma_f32_16x16x32_f16(ah[m], wh, acc1[m][bn], 0, 0, 0);
        acc1[m][bn] = __builtin_amdgcn_mfma_f32_16x16x32_f16(ah[m], wl, acc1[m][bn], 0, 0, 0);
        acc1[m][bn] = __builtin_amdgcn_mfma_f32_16x16x32_f16(al[m], wh, acc1[m][bn], 0, 0, 0);
      }
    }
  }

  // ---- bias + fp32 row L2-norms (C/D layout: col=l15, row=quad*4+r) ----
  float bpv[4];
  #pragma unroll
  for (int bn = 0; bn < 4; ++bn) bpv[bn] = bp[(w << 6) + (bn << 4) + l15];
  float n2[4][4];
  #pragma unroll
  for (int m = 0; m < 4; ++m)
    #pragma unroll
    for (int r = 0; r < 4; ++r) {
      float s = 0.f;
      #pragma unroll
      for (int bn = 0; bn < 4; ++bn) {
        float v = acc1[m][bn][r] + bpv[bn];
        acc1[m][bn][r] = v;
        s = fmaf(v, v, s);
      }
      n2[m][r] = s;
    }
  #pragma unroll
  for (int off = 1; off < 16; off <<= 1)
    #pragma unroll
    for (int m = 0; m < 4; ++m)
      #pragma unroll
      for (int r = 0; r < 4; ++r) n2[m][r] += __shfl_xor(n2[m][r], off, 64);

  __syncthreads();   // (A) all GEMM1 LDS reads done
  // cross-wave norm exchange via ushort bit-halves (no type punning)
  if (l15 == 0) {
    #pragma unroll
    for (int m = 0; m < 4; ++m)
      #pragma unroll
      for (int r = 0; r < 4; ++r) {
        int i = (w << 6) + (m << 4) + (quad << 2) + r;
        unsigned u = __float_as_uint(n2[m][r]);
        smu[i << 1] = (unsigned short)u;
        smu[(i << 1) + 1] = (unsigned short)(u >> 16);
      }
  }
  __syncthreads();   // (B)
  float rn[4][4];
  #pragma unroll
  for (int m = 0; m < 4; ++m)
    #pragma unroll
    for (int r = 0; r < 4; ++r) {
      int s = (m << 4) + (quad << 2) + r;
      float t = 0.f;
      #pragma unroll
      for (int ww = 0; ww < 4; ++ww) {
        int i = (ww << 6) + s;
        unsigned u = (unsigned)smu[i << 1] | ((unsigned)smu[(i << 1) + 1] << 16);
        t += __uint_as_float(u);
      }
      rn[m][r] = 1.f / fmaxf(sqrtf(t), 1e-12f);
    }
  __syncthreads();   // (C) norm reads done, LDS reusable

  // ---- writeback normalized k as GEMM2 B-operand: kn[s][b], swizzled ----
  unsigned short* kn_hi = smu;
  unsigned short* kn_lo = smu + 16384;
  #pragma unroll
  for (int m = 0; m < 4; ++m)
    #pragma unroll
    for (int bn = 0; bn < 4; ++bn)
      #pragma unroll
      for (int r = 0; r < 4; ++r) {
        int s = (m << 4) + (quad << 2) + r;
        int b = (w << 6) + (bn << 4) + l15;
        float v = acc1[m][bn][r] * rn[m][r];
        _Float16 h = (_Float16)v;
        _Float16 lo = (_Float16)(v - (float)h);
        int p = (b >> 3) ^ (s & 15);
        int off = (s << 8) + (p << 3) + (b & 7);
        *(_Float16*)(kn_hi + off) = h;
        *(_Float16*)(kn_lo + off) = lo;
      }
  __syncthreads();   // (D)

  // ---- GEMM2: logits[l][s] = sum_b q[l][b] * kn[s][b] (3-term split) ----
  f32x4 acc2[2][4];   // [m: l-tile][sn: s-tile]; wave w owns l in [w*32,w*32+32)
  #pragma unroll
  for (int m = 0; m < 2; ++m)
    #pragma unroll
    for (int sn = 0; sn < 4; ++sn) acc2[m][sn] = (f32x4)(0.0f);

  const _Float16* qhb = q_hi + (n << 15);
  const _Float16* qlb = q_lo + (n << 15);
  for (int kk = 0; kk < 8; ++kk) {
    int b0 = (kk << 5) + (quad << 3);
    half8 qh[2], ql[2];
    #pragma unroll
    for (int m = 0; m < 2; ++m) {
      int l = (w << 5) + (m << 4) + l15;
      qh[m] = *(const half8*)(qhb + (l << 8) + b0);
      ql[m] = *(const half8*)(qlb + (l << 8) + b0);
    }
    #pragma unroll
    for (int sn = 0; sn < 4; ++sn) {
      int s = (sn << 4) + l15;
      int p = (b0 >> 3) ^ l15;
      half8 kh = *(const half8*)(kn_hi + (s << 8) + (p << 3));
      half8 kl = *(const half8*)(kn_lo + (s << 8) + (p << 3));
      #pragma unroll
      for (int m = 0; m < 2; ++m) {
        acc2[m][sn] = __builtin_amdgcn_mfma_f32_16x16x32_f16(qh[m], kh, acc2[m][sn], 0, 0, 0);
        acc2[m][sn] = __builtin_amdgcn_mfma_f32_16x16x32_f16(qh[m], kl, acc2[m][sn], 0, 0, 0);
        acc2[m][sn] = __builtin_amdgcn_mfma_f32_16x16x32_f16(ql[m], kh, acc2[m][sn], 0, 0, 0);
      }
    }
  }

  // ---- fused argmax over this tile's 64 s (ties -> min s) ----
  float mv[8];
  int mi[8];
  #pragma unroll
  for (int m = 0; m < 2; ++m)
    #pragma unroll
    for (int r = 0; r < 4; ++r) {
      int i = (m << 2) + r;
      mv[i] = acc2[m][0][r];
      mi[i] = s_base + l15;
      #pragma unroll
      for (int sn = 1; sn < 4; ++sn) {
        float v = acc2[m][sn][r];
        int si = s_base + (sn << 4) + l15;
        if (v > mv[i]) { mv[i] = v; mi[i] = si; }
      }
    }
  #pragma unroll
  for (int off = 1; off < 16; off <<= 1)
    #pragma unroll
    for (int i = 0; i < 8; ++i) {
      float ov = __shfl_xor(mv[i], off, 64);
      int oi = __shfl_xor(mi[i], off, 64);
      if (ov > mv[i] || (ov == mv[i] && oi < mi[i])) { mv[i] = ov; mi[i] = oi; }
    }
  if (l15 == 0) {
    #pragma unroll
    for (int i = 0; i < 8; ++i) {
      int m = i >> 2, r = i & 3;
      int l = (w << 5) + (m << 4) + (quad << 2) + r;
      unsigned ub = __float_as_uint(mv[i]);
      ub = (ub & 0x80000000u) ? ~ub : (ub | 0x80000000u);
      unsigned long long pk = ((unsigned long long)ub << 32) |
                              (unsigned long long)(16383u - (unsigned)mi[i]);
      atomicMax(packed + (n << 7) + l, pk);
    }
  }
}

// ---------------------------------------------------------------------------
// Gather winners, recompute k_proj/v_proj (fp32) for the 1024 selected rows,
// output projection, residual, LayerNorm. 4 rows per block, 256 blocks.
__global__ __launch_bounds__(256) void k_final(
    const float* __restrict__ tgt,
    const float* __restrict__ memory, const float* __restrict__ pos,
    const float* __restrict__ WpT, const float* __restrict__ bp,
    const float* __restrict__ WvT, const float* __restrict__ bv,
    const float* __restrict__ WoT, const float* __restrict__ bo,
    const float* __restrict__ gamma, const float* __restrict__ beta,
    const unsigned long long* __restrict__ packed, float* __restrict__ out) {
  __shared__ __align__(16) float buf0[4][256];
  __shared__ __align__(16) float buf1[4][256];
  __shared__ __align__(16) float buf2[4][256];
  __shared__ float red[4][4][2];
  int tid = threadIdx.x;
  int r0 = blockIdx.x << 2;

  #pragma unroll
  for (int j = 0; j < 4; ++j) {
    int p = (j << 8) + tid;
    int rl = p >> 8, c = p & 255;
    int r = r0 + rl;
    int l = r >> 3, nn = r & 7;
    unsigned long long pk = packed[(nn << 7) + l];
    int sstar = (16383 - (int)(unsigned int)(pk & 0xffffffffu)) & 16383;
    int g = ((sstar << 3) + nn) * 256 + c;
    buf0[rl][c] = memory[g] + pos[g];
  }
  __syncthreads();

  float a[4];
  { float b0v = bp[tid];
    #pragma unroll
    for (int rl = 0; rl < 4; ++rl) a[rl] = b0v; }
  #pragma unroll 4
  for (int c = 0; c < 256; ++c) {
    float w = WpT[(c << 8) + tid];
    #pragma unroll
    for (int rl = 0; rl < 4; ++rl) a[rl] = fmaf(w, buf0[rl][c], a[rl]);
  }
  #pragma unroll
  for (int rl = 0; rl < 4; ++rl) buf1[rl][tid] = a[rl];
  __syncthreads();

  { float b0v = bv[tid];
    #pragma unroll
    for (int rl = 0; rl < 4; ++rl) a[rl] = b0v; }
  #pragma unroll 4
  for (int c = 0; c < 256; ++c) {
    float w = WvT[(c << 8) + tid];
    #pragma unroll
    for (int rl = 0; rl < 4; ++rl) a[rl] = fmaf(w, buf1[rl][c], a[rl]);
  }
  #pragma unroll
  for (int rl = 0; rl < 4; ++rl) buf2[rl][tid] = a[rl];
  __syncthreads();

  { float b0v = bo[tid];
    #pragma unroll
    for (int rl = 0; rl < 4; ++rl) a[rl] = b0v; }
  #pragma unroll 4
  for (int c = 0; c < 256; ++c) {
    float w = WoT[(c << 8) + tid];
    #pragma unroll
    for (int rl = 0; rl < 4; ++rl) a[rl] = fmaf(w, buf2[rl][c], a[rl]);
  }
  float x[4];
  #pragma unroll
  for (int rl = 0; rl < 4; ++rl)
    x[rl] = tgt[((r0 + rl) << 8) + tid] + a[rl];

  float s1[4], s2[4];
  #pragma unroll
  for (int rl = 0; rl < 4; ++rl) { s1[rl] = x[rl]; s2[rl] = x[rl] * x[rl]; }
  #pragma unroll
  for (int off = 1; off < 64; off <<= 1)
    #pragma unroll
    for (int rl = 0; rl < 4; ++rl) {
      s1[rl] += __shfl_xor(s1[rl], off, 64);
      s2[rl] += __shfl_xor(s2[rl], off, 64);
    }
  int wv = tid >> 6, ln = tid & 63;
  if (ln == 0) {
    #pragma unroll
    for (int rl = 0; rl < 4; ++rl) { red[wv][rl][0] = s1[rl]; red[wv][rl][1] = s2[rl]; }
  }
  __syncthreads();
  float g = gamma[tid], be = beta[tid];
  #pragma unroll
  for (int rl = 0; rl < 4; ++rl) {
    float S1 = red[0][rl][0] + red[1][rl][0] + red[2][rl][0] + red[3][rl][0];
    float S2 = red[0][rl][1] + red[1][rl][1] + red[2][rl][1] + red[3][rl][1];
    float mu = S1 * (1.f / 256.f);
    float var = S2 * (1.f / 256.f) - mu * mu;
    float rs = rsqrtf(var + 1e-5f);
    out[((r0 + rl) << 8) + tid] = (x[rl] - mu) * rs * g + be;
  }
}

// ---------------------------------------------------------------------------
extern "C" void kernel_launch(void* const* d_in, const int* in_sizes, int n_in,
                              void* d_out, int out_size, void* d_ws, size_t ws_size,
                              hipStream_t stream) {
  const float* tgt    = (const float*)d_in[0];
  const float* memory = (const float*)d_in[1];
  const float* pos    = (const float*)d_in[2];
  const float* qpos   = (const float*)d_in[3];
  const float* Wq     = (const float*)d_in[4];
  const float* bq     = (const float*)d_in[5];
  const float* Wp     = (const float*)d_in[6];
  const float* bp     = (const float*)d_in[7];
  const float* Wv     = (const float*)d_in[8];
  const float* bv     = (const float*)d_in[9];
  const float* Wo     = (const float*)d_in[10];
  const float* bo     = (const float*)d_in[11];
  const float* gamma  = (const float*)d_in[12];
  const float* beta   = (const float*)d_in[13];

  float* ws = (float*)d_ws;
  float* WpT = ws;                                   // [0, 65536)
  float* WvT = ws + 65536;                           // [65536, 131072)
  float* WoT = ws + 131072;                          // [131072, 196608)
  _Float16* Wp_hi = (_Float16*)(ws + 196608);        // 65536 halves
  _Float16* Wp_lo = (_Float16*)(ws + 229376);        // 65536 halves
  _Float16* q_hi  = (_Float16*)(ws + 262144);        // 262144 halves
  _Float16* q_lo  = (_Float16*)(ws + 393216);        // 262144 halves
  unsigned long long* packed = (unsigned long long*)(ws + 524288);  // 1024 u64
  float* out = (float*)d_out;

  k_prep<<<256, 256, 0, stream>>>(Wp, Wv, Wo, WpT, WvT, WoT, Wp_hi, Wp_lo, packed);
  k_qproj<<<256, 256, 0, stream>>>(tgt, qpos, Wq, bq, q_hi, q_lo);
  dim3 gb(S_P / 64, N_B);
  k_main<<<gb, 256, 0, stream>>>(memory, pos, Wp_hi, Wp_lo, bp, q_hi, q_lo, packed);
  k_final<<<256, 256, 0, stream>>>(tgt, memory, pos, WpT, bp, WvT, bv,
                                   WoT, bo, gamma, beta, packed, out);
}